// Round 1
// baseline (5780.149 us; speedup 1.0000x reference)
//
#include <hip/hip_runtime.h>

#define N_NODES 50000
#define N_EDGES 800000
#define D 128

typedef __bf16 bf16x8 __attribute__((ext_vector_type(8)));
typedef short s16x8 __attribute__((ext_vector_type(8)));
typedef short s16x4 __attribute__((ext_vector_type(4)));
typedef float f32x4 __attribute__((ext_vector_type(4)));
typedef unsigned short u16;

__device__ inline u16 f32_to_bf16(float f) {
    unsigned int u = __builtin_bit_cast(unsigned int, f);
    u += 0x7fffu + ((u >> 16) & 1u);   // round-to-nearest-even (inputs are finite/normal)
    return (u16)(u >> 16);
}
__device__ inline float bf16_to_f32(u16 h) {
    unsigned int u = ((unsigned int)h) << 16;
    return __builtin_bit_cast(float, u);
}

__device__ inline f32x4 mfma16(s16x8 a, s16x8 b, f32x4 c) {
    return __builtin_amdgcn_mfma_f32_16x16x32_bf16(
        __builtin_bit_cast(bf16x8, a), __builtin_bit_cast(bf16x8, b), c, 0, 0, 0);
}

// Pack W (128x128 f32, row-major, layout W[k][n]) into MFMA B-fragment order:
// Wp[((ct*4+ks)*64+lane)*8 + j] = bf16(W[(ks*32+(lane>>4)*8+j)*128 + ct*16+(lane&15)])
__global__ void prep_weights(const float* __restrict__ W0l, const float* __restrict__ W0r,
                             const float* __restrict__ W1l, const float* __restrict__ W1r,
                             u16* __restrict__ Wp) {
    int gid = blockIdx.x * blockDim.x + threadIdx.x;
    if (gid >= 4 * 2048) return;
    int wsel = gid >> 11;
    int rem  = gid & 2047;
    int ct   = rem >> 8;         // 0..7
    int ks   = (rem >> 6) & 3;   // 0..3
    int lane = rem & 63;
    const float* W = (wsel == 0) ? W0l : (wsel == 1) ? W0r : (wsel == 2) ? W1l : W1r;
    int n  = ct * 16 + (lane & 15);
    int k0 = ks * 32 + (lane >> 4) * 8;
    u16 o[8];
#pragma unroll
    for (int j = 0; j < 8; j++) o[j] = f32_to_bf16(W[(k0 + j) * D + n]);
    u16* dst = Wp + wsel * 16384 + (size_t)((ct * 4 + ks) * 64 + lane) * 8;
    *(s16x8*)dst = *(const s16x8*)o;
}

__global__ void cast_f32_bf16(const float* __restrict__ x, u16* __restrict__ xb, int n8) {
    int gid = blockIdx.x * blockDim.x + threadIdx.x;
    if (gid >= n8) return;
    const float* p = x + (size_t)gid * 8;
    f32x4 a = *(const f32x4*)p;
    f32x4 b = *(const f32x4*)(p + 4);
    u16 o[8];
#pragma unroll
    for (int j = 0; j < 4; j++) { o[j] = f32_to_bf16(a[j]); o[4 + j] = f32_to_bf16(b[j]); }
    *(s16x8*)(xb + (size_t)gid * 8) = *(const s16x8*)o;
}

__global__ void deg_kernel(const int* __restrict__ dst, int* __restrict__ deg, int n) {
    int gid = blockIdx.x * blockDim.x + threadIdx.x;
    if (gid < n) atomicAdd(&deg[dst[gid]], 1);
}

__global__ void inv_kernel(const int* __restrict__ deg, float* __restrict__ inv, int n) {
    int gid = blockIdx.x * blockDim.x + threadIdx.x;
    if (gid < n) {
        int d = deg[gid];
        inv[gid] = d > 0 ? 1.0f / (float)d : 0.0f;
    }
}

// Fused GEMM: m = A@Wl + b (bf16 out), s = A@Wr (f32 out). A is M x 128 bf16.
// Block = 4 waves, 64 rows x 256 logical cols (wave0/1 -> Wl cols 0-63/64-127, wave2/3 -> Wr).
__global__ __launch_bounds__(256) void gemm_sage(
    const u16* __restrict__ A, const u16* __restrict__ Wpl, const u16* __restrict__ Wpr,
    const float* __restrict__ bias, u16* __restrict__ mout, float* __restrict__ sout, int M) {
    int wave = threadIdx.x >> 6, lane = threadIdx.x & 63;
    int rowbase = blockIdx.x * 64;
    bool is_l = wave < 2;
    const u16* Wp = is_l ? Wpl : Wpr;
    int colbase = (wave & 1) * 64;
    int lrow = lane & 15, quad = lane >> 4;

    // Preload B fragments (stay in registers for the whole block)
    s16x8 bfrag[4][4];
#pragma unroll
    for (int ct = 0; ct < 4; ct++) {
        int ctg = (wave & 1) * 4 + ct;
#pragma unroll
        for (int ks = 0; ks < 4; ks++)
            bfrag[ct][ks] = *(const s16x8*)(Wp + (size_t)((ctg * 4 + ks) * 64 + lane) * 8);
    }

    f32x4 acc[4][4];
#pragma unroll
    for (int rt = 0; rt < 4; rt++)
#pragma unroll
        for (int ct = 0; ct < 4; ct++) acc[rt][ct] = (f32x4){0.f, 0.f, 0.f, 0.f};

#pragma unroll
    for (int ks = 0; ks < 4; ks++) {
        s16x8 afrag[4];
#pragma unroll
        for (int rt = 0; rt < 4; rt++) {
            int row = rowbase + rt * 16 + lrow;
            row = row < M ? row : M - 1;
            afrag[rt] = *(const s16x8*)(A + (size_t)row * D + ks * 32 + quad * 8);
        }
#pragma unroll
        for (int rt = 0; rt < 4; rt++)
#pragma unroll
            for (int ct = 0; ct < 4; ct++)
                acc[rt][ct] = mfma16(afrag[rt], bfrag[ct][ks], acc[rt][ct]);
    }

    float bv[4];
    if (is_l) {
#pragma unroll
        for (int ct = 0; ct < 4; ct++) bv[ct] = bias[colbase + ct * 16 + lrow];
    }
#pragma unroll
    for (int rt = 0; rt < 4; rt++) {
#pragma unroll
        for (int ct = 0; ct < 4; ct++) {
            int col = colbase + ct * 16 + lrow;
#pragma unroll
            for (int i = 0; i < 4; i++) {
                int row = rowbase + rt * 16 + quad * 4 + i;
                if (row >= M) continue;
                float v = acc[rt][ct][i];
                if (is_l) mout[(size_t)row * D + col] = f32_to_bf16(v + bv[ct]);
                else      sout[(size_t)row * D + col] = v;
            }
        }
    }
}

// 16 lanes per edge; each lane: 16B bf16 gather of m[src] + 8 f32 atomic adds to agg[dst].
__global__ void scatter_kernel(const u16* __restrict__ m, const int* __restrict__ src,
                               const int* __restrict__ dst, float* __restrict__ agg, int ne) {
    int gid = blockIdx.x * blockDim.x + threadIdx.x;
    int e = gid >> 4;
    if (e >= ne) return;
    int part = gid & 15;
    int s = src[e], d = dst[e];
    s16x8 v = *(const s16x8*)(m + (size_t)s * D + part * 8);
    float* ap = agg + (size_t)d * D + part * 8;
#pragma unroll
    for (int j = 0; j < 8; j++) unsafeAtomicAdd(ap + j, bf16_to_f32((u16)v[j]));
}

__global__ void combine_relu(const float* __restrict__ agg, const float* __restrict__ inv,
                             const float* __restrict__ s, u16* __restrict__ hb, int n4) {
    int gid = blockIdx.x * blockDim.x + threadIdx.x;
    if (gid >= n4) return;
    int r = gid >> 5;
    int c = (gid & 31) * 4;
    float iv = inv[r];
    f32x4 a  = *(const f32x4*)(agg + (size_t)r * D + c);
    f32x4 sv = *(const f32x4*)(s + (size_t)r * D + c);
    u16 o[4];
#pragma unroll
    for (int j = 0; j < 4; j++) {
        float v = a[j] * iv + sv[j];
        v = v > 0.f ? v : 0.f;
        o[j] = f32_to_bf16(v);
    }
    *(s16x4*)(hb + (size_t)r * D + c) = *(const s16x4*)o;
}

__global__ void combine_out(const float* __restrict__ agg, const float* __restrict__ inv,
                            const float* __restrict__ s, float* __restrict__ out, int n4) {
    int gid = blockIdx.x * blockDim.x + threadIdx.x;
    if (gid >= n4) return;
    int r = gid >> 5;
    int c = (gid & 31) * 4;
    float iv = inv[r];
    f32x4 a  = *(const f32x4*)(agg + (size_t)r * D + c);
    f32x4 sv = *(const f32x4*)(s + (size_t)r * D + c);
    f32x4 o;
#pragma unroll
    for (int j = 0; j < 4; j++) o[j] = a[j] * iv + sv[j];
    *(f32x4*)(out + (size_t)r * D + c) = o;
}

extern "C" void kernel_launch(void* const* d_in, const int* in_sizes, int n_in,
                              void* d_out, int out_size, void* d_ws, size_t ws_size,
                              hipStream_t stream) {
    const float* x    = (const float*)d_in[0];
    const int*   edge = (const int*)d_in[1];
    const int*   src  = edge;
    const int*   dstn = edge + N_EDGES;
    const float* W0l  = (const float*)d_in[2];
    const float* b0l  = (const float*)d_in[3];
    const float* W0r  = (const float*)d_in[4];
    const float* W1l  = (const float*)d_in[5];
    const float* b1l  = (const float*)d_in[6];
    const float* W1r  = (const float*)d_in[7];
    float* out = (float*)d_out;

    char* p = (char*)d_ws;
    auto alloc = [&](size_t nb) { char* r = p; p += (nb + 255) & ~(size_t)255; return r; };
    int*   deg  = (int*)alloc((size_t)N_NODES * 4);
    float* inv  = (float*)alloc((size_t)N_NODES * 4);
    u16*   xb   = (u16*)alloc((size_t)N_NODES * D * 2);
    u16*   hb   = (u16*)alloc((size_t)N_NODES * D * 2);
    u16*   mb   = (u16*)alloc((size_t)N_NODES * D * 2);
    float* sbuf = (float*)alloc((size_t)N_NODES * D * 4);
    float* agg  = (float*)alloc((size_t)N_NODES * D * 4);
    u16*   Wp   = (u16*)alloc((size_t)4 * 16384 * 2);

    hipMemsetAsync(deg, 0, (size_t)N_NODES * 4, stream);
    hipMemsetAsync(agg, 0, (size_t)N_NODES * D * 4, stream);

    prep_weights<<<(8192 + 255) / 256, 256, 0, stream>>>(W0l, W0r, W1l, W1r, Wp);
    cast_f32_bf16<<<(N_NODES * 16 + 255) / 256, 256, 0, stream>>>(x, xb, N_NODES * 16);
    deg_kernel<<<(N_EDGES + 255) / 256, 256, 0, stream>>>(dstn, deg, N_EDGES);
    inv_kernel<<<(N_NODES + 255) / 256, 256, 0, stream>>>(deg, inv, N_NODES);

    int mblocks = (N_NODES + 63) / 64;
    // Layer 0
    gemm_sage<<<mblocks, 256, 0, stream>>>(xb, Wp, Wp + 16384, b0l, mb, sbuf, N_NODES);
    scatter_kernel<<<(N_EDGES * 16 + 255) / 256, 256, 0, stream>>>(mb, src, dstn, agg, N_EDGES);
    combine_relu<<<(N_NODES * 32 + 255) / 256, 256, 0, stream>>>(agg, inv, sbuf, hb, N_NODES * 32);
    // Layer 1
    hipMemsetAsync(agg, 0, (size_t)N_NODES * D * 4, stream);
    gemm_sage<<<mblocks, 256, 0, stream>>>(hb, Wp + 2 * 16384, Wp + 3 * 16384, b1l, mb, sbuf, N_NODES);
    scatter_kernel<<<(N_EDGES * 16 + 255) / 256, 256, 0, stream>>>(mb, src, dstn, agg, N_EDGES);
    combine_out<<<(N_NODES * 32 + 255) / 256, 256, 0, stream>>>(agg, inv, sbuf, out, N_NODES * 32);
}

// Round 2
// 421.378 us; speedup vs baseline: 13.7172x; 13.7172x over previous
//
#include <hip/hip_runtime.h>

#define N_NODES 50000
#define N_EDGES 800000
#define D 128

typedef __bf16 bf16x8 __attribute__((ext_vector_type(8)));
typedef short s16x8 __attribute__((ext_vector_type(8)));
typedef short s16x4 __attribute__((ext_vector_type(4)));
typedef float f32x4 __attribute__((ext_vector_type(4)));
typedef float f32x2 __attribute__((ext_vector_type(2)));
typedef unsigned short u16;
typedef unsigned int u32;

__device__ inline u16 f32_to_bf16(float f) {
    u32 u = __builtin_bit_cast(u32, f);
    u += 0x7fffu + ((u >> 16) & 1u);   // round-to-nearest-even
    return (u16)(u >> 16);
}
__device__ inline float bf16_lo(u32 v) { return __builtin_bit_cast(float, v << 16); }
__device__ inline float bf16_hi(u32 v) { return __builtin_bit_cast(float, v & 0xffff0000u); }

__device__ inline f32x4 mfma16(s16x8 a, s16x8 b, f32x4 c) {
    return __builtin_amdgcn_mfma_f32_16x16x32_bf16(
        __builtin_bit_cast(bf16x8, a), __builtin_bit_cast(bf16x8, b), c, 0, 0, 0);
}

// Pack W (128x128 f32, row-major W[k][n]) into MFMA B-fragment order.
__global__ void prep_weights(const float* __restrict__ W0l, const float* __restrict__ W0r,
                             const float* __restrict__ W1l, const float* __restrict__ W1r,
                             u16* __restrict__ Wp) {
    int gid = blockIdx.x * blockDim.x + threadIdx.x;
    if (gid >= 4 * 2048) return;
    int wsel = gid >> 11;
    int rem  = gid & 2047;
    int ct   = rem >> 8;         // 0..7
    int ks   = (rem >> 6) & 3;   // 0..3
    int lane = rem & 63;
    const float* W = (wsel == 0) ? W0l : (wsel == 1) ? W0r : (wsel == 2) ? W1l : W1r;
    int n  = ct * 16 + (lane & 15);
    int k0 = ks * 32 + (lane >> 4) * 8;
    u16 o[8];
#pragma unroll
    for (int j = 0; j < 8; j++) o[j] = f32_to_bf16(W[(k0 + j) * D + n]);
    u16* dst = Wp + wsel * 16384 + (size_t)((ct * 4 + ks) * 64 + lane) * 8;
    *(s16x8*)dst = *(const s16x8*)o;
}

__global__ void cast_f32_bf16(const float* __restrict__ x, u16* __restrict__ xb, int n8) {
    int gid = blockIdx.x * blockDim.x + threadIdx.x;
    if (gid >= n8) return;
    const float* p = x + (size_t)gid * 8;
    f32x4 a = *(const f32x4*)p;
    f32x4 b = *(const f32x4*)(p + 4);
    u16 o[8];
#pragma unroll
    for (int j = 0; j < 4; j++) { o[j] = f32_to_bf16(a[j]); o[4 + j] = f32_to_bf16(b[j]); }
    *(s16x8*)(xb + (size_t)gid * 8) = *(const s16x8*)o;
}

__global__ void deg_kernel(const int* __restrict__ dst, int* __restrict__ deg, int n) {
    int gid = blockIdx.x * blockDim.x + threadIdx.x;
    if (gid < n) atomicAdd(&deg[dst[gid]], 1);
}

// Single-block exclusive scan of deg -> rowptr; also writes inv_deg.
__global__ __launch_bounds__(1024) void scan_kernel(const int* __restrict__ deg,
                                                    int* __restrict__ rowptr,
                                                    float* __restrict__ inv) {
    __shared__ int partial[1024];
    int tid = threadIdx.x;
    const int PER = (N_NODES + 1023) / 1024;   // 49
    int base = tid * PER;
    int s = 0;
#pragma unroll 1
    for (int i = 0; i < PER; i++) {
        int idx = base + i;
        if (idx < N_NODES) s += deg[idx];
    }
    partial[tid] = s;
    __syncthreads();
    for (int off = 1; off < 1024; off <<= 1) {
        int v = partial[tid];
        int add = (tid >= off) ? partial[tid - off] : 0;
        __syncthreads();
        partial[tid] = v + add;
        __syncthreads();
    }
    int run = (tid == 0) ? 0 : partial[tid - 1];
#pragma unroll 1
    for (int i = 0; i < PER; i++) {
        int idx = base + i;
        if (idx < N_NODES) {
            rowptr[idx] = run;
            int d = deg[idx];
            inv[idx] = d > 0 ? 1.0f / (float)d : 0.0f;
            run += d;
        }
    }
    if (tid == 1023) rowptr[N_NODES] = run;
}

// Place src ids into CSR buckets (order within a bucket is arbitrary — sum is commutative
// up to fp rounding, well within threshold).
__global__ void bucket_kernel(const int* __restrict__ src, const int* __restrict__ dst,
                              int* __restrict__ cursor, int* __restrict__ eidx, int n) {
    int gid = blockIdx.x * blockDim.x + threadIdx.x;
    if (gid < n) {
        int pos = atomicAdd(&cursor[dst[gid]], 1);
        eidx[pos] = src[gid];
    }
}

// Fused GEMM: m = A@Wl + b (bf16 out), s = A@Wr (f32 out). A is M x 128 bf16.
__global__ __launch_bounds__(256) void gemm_sage(
    const u16* __restrict__ A, const u16* __restrict__ Wpl, const u16* __restrict__ Wpr,
    const float* __restrict__ bias, u16* __restrict__ mout, float* __restrict__ sout, int M) {
    int wave = threadIdx.x >> 6, lane = threadIdx.x & 63;
    int rowbase = blockIdx.x * 64;
    bool is_l = wave < 2;
    const u16* Wp = is_l ? Wpl : Wpr;
    int colbase = (wave & 1) * 64;
    int lrow = lane & 15, quad = lane >> 4;

    s16x8 bfrag[4][4];
#pragma unroll
    for (int ct = 0; ct < 4; ct++) {
        int ctg = (wave & 1) * 4 + ct;
#pragma unroll
        for (int ks = 0; ks < 4; ks++)
            bfrag[ct][ks] = *(const s16x8*)(Wp + (size_t)((ctg * 4 + ks) * 64 + lane) * 8);
    }

    f32x4 acc[4][4];
#pragma unroll
    for (int rt = 0; rt < 4; rt++)
#pragma unroll
        for (int ct = 0; ct < 4; ct++) acc[rt][ct] = (f32x4){0.f, 0.f, 0.f, 0.f};

#pragma unroll
    for (int ks = 0; ks < 4; ks++) {
        s16x8 afrag[4];
#pragma unroll
        for (int rt = 0; rt < 4; rt++) {
            int row = rowbase + rt * 16 + lrow;
            row = row < M ? row : M - 1;
            afrag[rt] = *(const s16x8*)(A + (size_t)row * D + ks * 32 + quad * 8);
        }
#pragma unroll
        for (int rt = 0; rt < 4; rt++)
#pragma unroll
            for (int ct = 0; ct < 4; ct++)
                acc[rt][ct] = mfma16(afrag[rt], bfrag[ct][ks], acc[rt][ct]);
    }

    float bv[4];
    if (is_l) {
#pragma unroll
        for (int ct = 0; ct < 4; ct++) bv[ct] = bias[colbase + ct * 16 + lrow];
    }
#pragma unroll
    for (int rt = 0; rt < 4; rt++) {
#pragma unroll
        for (int ct = 0; ct < 4; ct++) {
            int col = colbase + ct * 16 + lrow;
#pragma unroll
            for (int i = 0; i < 4; i++) {
                int row = rowbase + rt * 16 + quad * 4 + i;
                if (row >= M) continue;
                float v = acc[rt][ct][i];
                if (is_l) mout[(size_t)row * D + col] = f32_to_bf16(v + bv[ct]);
                else      sout[(size_t)row * D + col] = v;
            }
        }
    }
}

// One wave per destination node: gather m[src] rows via CSR, accumulate in registers,
// fuse mean + skip-add (+ReLU for layer 0). Lane l handles cols {2l, 2l+1}.
template <int RELU>
__global__ __launch_bounds__(256) void agg_combine(
    const u16* __restrict__ m, const int* __restrict__ rowptr, const int* __restrict__ eidx,
    const float* __restrict__ inv, const float* __restrict__ sbuf,
    u16* __restrict__ bf_out, float* __restrict__ f32_out) {
    int wave = threadIdx.x >> 6, lane = threadIdx.x & 63;
    int node = blockIdx.x * 4 + wave;
    if (node >= N_NODES) return;
    int start = rowptr[node], end = rowptr[node + 1];

    float a0 = 0.f, a1 = 0.f;
    int e = start;
    for (; e + 3 < end; e += 4) {
        int s0 = eidx[e], s1 = eidx[e + 1], s2 = eidx[e + 2], s3 = eidx[e + 3];
        u32 v0 = *(const u32*)(m + (size_t)s0 * D + lane * 2);
        u32 v1 = *(const u32*)(m + (size_t)s1 * D + lane * 2);
        u32 v2 = *(const u32*)(m + (size_t)s2 * D + lane * 2);
        u32 v3 = *(const u32*)(m + (size_t)s3 * D + lane * 2);
        a0 += bf16_lo(v0) + bf16_lo(v1) + bf16_lo(v2) + bf16_lo(v3);
        a1 += bf16_hi(v0) + bf16_hi(v1) + bf16_hi(v2) + bf16_hi(v3);
    }
    for (; e < end; e++) {
        int s0 = eidx[e];
        u32 v0 = *(const u32*)(m + (size_t)s0 * D + lane * 2);
        a0 += bf16_lo(v0);
        a1 += bf16_hi(v0);
    }

    float iv = inv[node];
    f32x2 sp = *(const f32x2*)(sbuf + (size_t)node * D + lane * 2);
    float r0 = a0 * iv + sp[0];
    float r1 = a1 * iv + sp[1];
    if (RELU) {
        r0 = r0 > 0.f ? r0 : 0.f;
        r1 = r1 > 0.f ? r1 : 0.f;
        u32 packed = (u32)f32_to_bf16(r0) | ((u32)f32_to_bf16(r1) << 16);
        *(u32*)(bf_out + (size_t)node * D + lane * 2) = packed;
    } else {
        f32x2 o; o[0] = r0; o[1] = r1;
        *(f32x2*)(f32_out + (size_t)node * D + lane * 2) = o;
    }
}

extern "C" void kernel_launch(void* const* d_in, const int* in_sizes, int n_in,
                              void* d_out, int out_size, void* d_ws, size_t ws_size,
                              hipStream_t stream) {
    const float* x    = (const float*)d_in[0];
    const int*   edge = (const int*)d_in[1];
    const int*   src  = edge;
    const int*   dstn = edge + N_EDGES;
    const float* W0l  = (const float*)d_in[2];
    const float* b0l  = (const float*)d_in[3];
    const float* W0r  = (const float*)d_in[4];
    const float* W1l  = (const float*)d_in[5];
    const float* b1l  = (const float*)d_in[6];
    const float* W1r  = (const float*)d_in[7];
    float* out = (float*)d_out;

    char* p = (char*)d_ws;
    auto alloc = [&](size_t nb) { char* r = p; p += (nb + 255) & ~(size_t)255; return r; };
    int*   deg    = (int*)alloc((size_t)N_NODES * 4);
    int*   rowptr = (int*)alloc((size_t)(N_NODES + 1) * 4);
    int*   cursor = (int*)alloc((size_t)N_NODES * 4);
    int*   eidx   = (int*)alloc((size_t)N_EDGES * 4);
    float* inv    = (float*)alloc((size_t)N_NODES * 4);
    u16*   xb     = (u16*)alloc((size_t)N_NODES * D * 2);
    u16*   hb     = (u16*)alloc((size_t)N_NODES * D * 2);
    u16*   mb     = (u16*)alloc((size_t)N_NODES * D * 2);
    float* sbuf   = (float*)alloc((size_t)N_NODES * D * 4);
    u16*   Wp     = (u16*)alloc((size_t)4 * 16384 * 2);

    hipMemsetAsync(deg, 0, (size_t)N_NODES * 4, stream);

    prep_weights<<<(8192 + 255) / 256, 256, 0, stream>>>(W0l, W0r, W1l, W1r, Wp);
    cast_f32_bf16<<<(N_NODES * 16 + 255) / 256, 256, 0, stream>>>(x, xb, N_NODES * 16);
    deg_kernel<<<(N_EDGES + 255) / 256, 256, 0, stream>>>(dstn, deg, N_EDGES);
    scan_kernel<<<1, 1024, 0, stream>>>(deg, rowptr, inv);
    hipMemcpyAsync(cursor, rowptr, (size_t)N_NODES * 4, hipMemcpyDeviceToDevice, stream);
    bucket_kernel<<<(N_EDGES + 255) / 256, 256, 0, stream>>>(src, dstn, cursor, eidx, N_EDGES);

    int mblocks = (N_NODES + 63) / 64;
    int ablocks = (N_NODES + 3) / 4;
    // Layer 0
    gemm_sage<<<mblocks, 256, 0, stream>>>(xb, Wp, Wp + 16384, b0l, mb, sbuf, N_NODES);
    agg_combine<1><<<ablocks, 256, 0, stream>>>(mb, rowptr, eidx, inv, sbuf, hb, nullptr);
    // Layer 1
    gemm_sage<<<mblocks, 256, 0, stream>>>(hb, Wp + 2 * 16384, Wp + 3 * 16384, b1l, mb, sbuf, N_NODES);
    agg_combine<0><<<ablocks, 256, 0, stream>>>(mb, rowptr, eidx, inv, sbuf, nullptr, out);
}

// Round 3
// 303.810 us; speedup vs baseline: 19.0255x; 1.3870x over previous
//
#include <hip/hip_runtime.h>

#define N_NODES 50000
#define N_EDGES 800000
#define D 128
#define NBLK ((N_NODES + 255) / 256)   // 196 scan blocks

typedef __bf16 bf16x8 __attribute__((ext_vector_type(8)));
typedef short s16x8 __attribute__((ext_vector_type(8)));
typedef short s16x4 __attribute__((ext_vector_type(4)));
typedef float f32x4 __attribute__((ext_vector_type(4)));
typedef float f32x2 __attribute__((ext_vector_type(2)));
typedef unsigned short u16;
typedef unsigned int u32;

__device__ inline u16 f32_to_bf16(float f) {
    u32 u = __builtin_bit_cast(u32, f);
    u += 0x7fffu + ((u >> 16) & 1u);   // round-to-nearest-even
    return (u16)(u >> 16);
}
__device__ inline float bf16_lo(u32 v) { return __builtin_bit_cast(float, v << 16); }
__device__ inline float bf16_hi(u32 v) { return __builtin_bit_cast(float, v & 0xffff0000u); }

__device__ inline f32x4 mfma16(s16x8 a, s16x8 b, f32x4 c) {
    return __builtin_amdgcn_mfma_f32_16x16x32_bf16(
        __builtin_bit_cast(bf16x8, a), __builtin_bit_cast(bf16x8, b), c, 0, 0, 0);
}

// Pack W (128x128 f32, row-major W[k][n]) into MFMA B-fragment order.
__global__ void prep_weights(const float* __restrict__ W0l, const float* __restrict__ W0r,
                             const float* __restrict__ W1l, const float* __restrict__ W1r,
                             u16* __restrict__ Wp) {
    int gid = blockIdx.x * blockDim.x + threadIdx.x;
    if (gid >= 4 * 2048) return;
    int wsel = gid >> 11;
    int rem  = gid & 2047;
    int ct   = rem >> 8;         // 0..7
    int ks   = (rem >> 6) & 3;   // 0..3
    int lane = rem & 63;
    const float* W = (wsel == 0) ? W0l : (wsel == 1) ? W0r : (wsel == 2) ? W1l : W1r;
    int n  = ct * 16 + (lane & 15);
    int k0 = ks * 32 + (lane >> 4) * 8;
    u16 o[8];
#pragma unroll
    for (int j = 0; j < 8; j++) o[j] = f32_to_bf16(W[(k0 + j) * D + n]);
    u16* dst = Wp + wsel * 16384 + (size_t)((ct * 4 + ks) * 64 + lane) * 8;
    *(s16x8*)dst = *(const s16x8*)o;
}

__global__ void cast_f32_bf16(const float* __restrict__ x, u16* __restrict__ xb, int n8) {
    int gid = blockIdx.x * blockDim.x + threadIdx.x;
    if (gid >= n8) return;
    const float* p = x + (size_t)gid * 8;
    f32x4 a = *(const f32x4*)p;
    f32x4 b = *(const f32x4*)(p + 4);
    u16 o[8];
#pragma unroll
    for (int j = 0; j < 4; j++) { o[j] = f32_to_bf16(a[j]); o[4 + j] = f32_to_bf16(b[j]); }
    *(s16x8*)(xb + (size_t)gid * 8) = *(const s16x8*)o;
}

__global__ void deg_kernel(const int* __restrict__ dst, int* __restrict__ deg, int n) {
    int gid = blockIdx.x * blockDim.x + threadIdx.x;
    if (gid < n) atomicAdd(&deg[dst[gid]], 1);
}

// Level 1: per-256-node block exclusive scan (wave shuffle + LDS), emit block totals.
__global__ __launch_bounds__(256) void scan1(const int* __restrict__ deg,
                                             int* __restrict__ part,
                                             int* __restrict__ blocksum) {
    int t = threadIdx.x, b = blockIdx.x;
    int idx = b * 256 + t;
    int v = (idx < N_NODES) ? deg[idx] : 0;
    int lane = t & 63, wave = t >> 6;
    int s = v;
#pragma unroll
    for (int off = 1; off < 64; off <<= 1) {
        int u = __shfl_up(s, off, 64);
        if (lane >= off) s += u;
    }
    __shared__ int wsum[4];
    if (lane == 63) wsum[wave] = s;
    __syncthreads();
    int wadd = 0;
#pragma unroll
    for (int w = 0; w < 4; w++) if (w < wave) wadd += wsum[w];
    if (idx < N_NODES) part[idx] = s - v + wadd;   // exclusive within block
    if (t == 255) blocksum[b] = wadd + s;
}

// Level 2: exclusive scan of the NBLK (=196) block sums, one small block.
__global__ __launch_bounds__(256) void scan2(const int* __restrict__ blocksum,
                                             int* __restrict__ blockoff) {
    int t = threadIdx.x;
    int v = (t < NBLK) ? blocksum[t] : 0;
    int lane = t & 63, wave = t >> 6;
    int s = v;
#pragma unroll
    for (int off = 1; off < 64; off <<= 1) {
        int u = __shfl_up(s, off, 64);
        if (lane >= off) s += u;
    }
    __shared__ int wsum[4];
    if (lane == 63) wsum[wave] = s;
    __syncthreads();
    int wadd = 0;
#pragma unroll
    for (int w = 0; w < 4; w++) if (w < wave) wadd += wsum[w];
    if (t < NBLK) blockoff[t] = s - v + wadd;
}

// Level 3: apply block offsets; write rowptr, cursor (bucket cursors), inv_deg.
__global__ __launch_bounds__(256) void scan3(const int* __restrict__ part,
                                             const int* __restrict__ blockoff,
                                             const int* __restrict__ deg,
                                             int* __restrict__ rowptr,
                                             int* __restrict__ cursor,
                                             float* __restrict__ inv) {
    int t = threadIdx.x, b = blockIdx.x;
    int idx = b * 256 + t;
    if (idx < N_NODES) {
        int r = part[idx] + blockoff[b];
        rowptr[idx] = r;
        cursor[idx] = r;
        int d = deg[idx];
        inv[idx] = d > 0 ? 1.0f / (float)d : 0.0f;
    }
    if (b == 0 && t == 0) rowptr[N_NODES] = N_EDGES;  // all dst are in-range
}

// Place src ids into CSR buckets (order within a bucket is arbitrary).
__global__ void bucket_kernel(const int* __restrict__ src, const int* __restrict__ dst,
                              int* __restrict__ cursor, int* __restrict__ eidx, int n) {
    int gid = blockIdx.x * blockDim.x + threadIdx.x;
    if (gid < n) {
        int pos = atomicAdd(&cursor[dst[gid]], 1);
        eidx[pos] = src[gid];
    }
}

// Fused GEMM: m = A@Wl + b (bf16 out), s = A@Wr (f32 out). A is M x 128 bf16.
__global__ __launch_bounds__(256) void gemm_sage(
    const u16* __restrict__ A, const u16* __restrict__ Wpl, const u16* __restrict__ Wpr,
    const float* __restrict__ bias, u16* __restrict__ mout, float* __restrict__ sout, int M) {
    int wave = threadIdx.x >> 6, lane = threadIdx.x & 63;
    int rowbase = blockIdx.x * 64;
    bool is_l = wave < 2;
    const u16* Wp = is_l ? Wpl : Wpr;
    int colbase = (wave & 1) * 64;
    int lrow = lane & 15, quad = lane >> 4;

    s16x8 bfrag[4][4];
#pragma unroll
    for (int ct = 0; ct < 4; ct++) {
        int ctg = (wave & 1) * 4 + ct;
#pragma unroll
        for (int ks = 0; ks < 4; ks++)
            bfrag[ct][ks] = *(const s16x8*)(Wp + (size_t)((ctg * 4 + ks) * 64 + lane) * 8);
    }

    f32x4 acc[4][4];
#pragma unroll
    for (int rt = 0; rt < 4; rt++)
#pragma unroll
        for (int ct = 0; ct < 4; ct++) acc[rt][ct] = (f32x4){0.f, 0.f, 0.f, 0.f};

#pragma unroll
    for (int ks = 0; ks < 4; ks++) {
        s16x8 afrag[4];
#pragma unroll
        for (int rt = 0; rt < 4; rt++) {
            int row = rowbase + rt * 16 + lrow;
            row = row < M ? row : M - 1;
            afrag[rt] = *(const s16x8*)(A + (size_t)row * D + ks * 32 + quad * 8);
        }
#pragma unroll
        for (int rt = 0; rt < 4; rt++)
#pragma unroll
            for (int ct = 0; ct < 4; ct++)
                acc[rt][ct] = mfma16(afrag[rt], bfrag[ct][ks], acc[rt][ct]);
    }

    float bv[4];
    if (is_l) {
#pragma unroll
        for (int ct = 0; ct < 4; ct++) bv[ct] = bias[colbase + ct * 16 + lrow];
    }
#pragma unroll
    for (int rt = 0; rt < 4; rt++) {
#pragma unroll
        for (int ct = 0; ct < 4; ct++) {
            int col = colbase + ct * 16 + lrow;
#pragma unroll
            for (int i = 0; i < 4; i++) {
                int row = rowbase + rt * 16 + quad * 4 + i;
                if (row >= M) continue;
                float v = acc[rt][ct][i];
                if (is_l) mout[(size_t)row * D + col] = f32_to_bf16(v + bv[ct]);
                else      sout[(size_t)row * D + col] = v;
            }
        }
    }
}

// One wave per destination node: gather m[src] rows via CSR, accumulate in registers,
// fuse mean + skip-add (+ReLU for layer 0). Lane l handles cols {2l, 2l+1}.
template <int RELU>
__global__ __launch_bounds__(256) void agg_combine(
    const u16* __restrict__ m, const int* __restrict__ rowptr, const int* __restrict__ eidx,
    const float* __restrict__ inv, const float* __restrict__ sbuf,
    u16* __restrict__ bf_out, float* __restrict__ f32_out) {
    int wave = threadIdx.x >> 6, lane = threadIdx.x & 63;
    int node = blockIdx.x * 4 + wave;
    if (node >= N_NODES) return;
    int start = rowptr[node], end = rowptr[node + 1];

    float a0 = 0.f, a1 = 0.f;
    int e = start;
    for (; e + 3 < end; e += 4) {
        int s0 = eidx[e], s1 = eidx[e + 1], s2 = eidx[e + 2], s3 = eidx[e + 3];
        u32 v0 = *(const u32*)(m + (size_t)s0 * D + lane * 2);
        u32 v1 = *(const u32*)(m + (size_t)s1 * D + lane * 2);
        u32 v2 = *(const u32*)(m + (size_t)s2 * D + lane * 2);
        u32 v3 = *(const u32*)(m + (size_t)s3 * D + lane * 2);
        a0 += bf16_lo(v0) + bf16_lo(v1) + bf16_lo(v2) + bf16_lo(v3);
        a1 += bf16_hi(v0) + bf16_hi(v1) + bf16_hi(v2) + bf16_hi(v3);
    }
    for (; e < end; e++) {
        int s0 = eidx[e];
        u32 v0 = *(const u32*)(m + (size_t)s0 * D + lane * 2);
        a0 += bf16_lo(v0);
        a1 += bf16_hi(v0);
    }

    float iv = inv[node];
    f32x2 sp = *(const f32x2*)(sbuf + (size_t)node * D + lane * 2);
    float r0 = a0 * iv + sp[0];
    float r1 = a1 * iv + sp[1];
    if (RELU) {
        r0 = r0 > 0.f ? r0 : 0.f;
        r1 = r1 > 0.f ? r1 : 0.f;
        u32 packed = (u32)f32_to_bf16(r0) | ((u32)f32_to_bf16(r1) << 16);
        *(u32*)(bf_out + (size_t)node * D + lane * 2) = packed;
    } else {
        f32x2 o; o[0] = r0; o[1] = r1;
        *(f32x2*)(f32_out + (size_t)node * D + lane * 2) = o;
    }
}

extern "C" void kernel_launch(void* const* d_in, const int* in_sizes, int n_in,
                              void* d_out, int out_size, void* d_ws, size_t ws_size,
                              hipStream_t stream) {
    const float* x    = (const float*)d_in[0];
    const int*   edge = (const int*)d_in[1];
    const int*   src  = edge;
    const int*   dstn = edge + N_EDGES;
    const float* W0l  = (const float*)d_in[2];
    const float* b0l  = (const float*)d_in[3];
    const float* W0r  = (const float*)d_in[4];
    const float* W1l  = (const float*)d_in[5];
    const float* b1l  = (const float*)d_in[6];
    const float* W1r  = (const float*)d_in[7];
    float* out = (float*)d_out;

    char* p = (char*)d_ws;
    auto alloc = [&](size_t nb) { char* r = p; p += (nb + 255) & ~(size_t)255; return r; };
    int*   deg    = (int*)alloc((size_t)N_NODES * 4);
    int*   part   = (int*)alloc((size_t)N_NODES * 4);
    int*   bsum   = (int*)alloc((size_t)NBLK * 4);
    int*   boff   = (int*)alloc((size_t)NBLK * 4);
    int*   rowptr = (int*)alloc((size_t)(N_NODES + 1) * 4);
    int*   cursor = (int*)alloc((size_t)N_NODES * 4);
    int*   eidx   = (int*)alloc((size_t)N_EDGES * 4);
    float* inv    = (float*)alloc((size_t)N_NODES * 4);
    u16*   xb     = (u16*)alloc((size_t)N_NODES * D * 2);
    u16*   hb     = (u16*)alloc((size_t)N_NODES * D * 2);
    u16*   mb     = (u16*)alloc((size_t)N_NODES * D * 2);
    float* sbuf   = (float*)alloc((size_t)N_NODES * D * 4);
    u16*   Wp     = (u16*)alloc((size_t)4 * 16384 * 2);

    hipMemsetAsync(deg, 0, (size_t)N_NODES * 4, stream);

    prep_weights<<<(8192 + 255) / 256, 256, 0, stream>>>(W0l, W0r, W1l, W1r, Wp);
    cast_f32_bf16<<<(N_NODES * 16 + 255) / 256, 256, 0, stream>>>(x, xb, N_NODES * 16);
    deg_kernel<<<(N_EDGES + 255) / 256, 256, 0, stream>>>(dstn, deg, N_EDGES);
    scan1<<<NBLK, 256, 0, stream>>>(deg, part, bsum);
    scan2<<<1, 256, 0, stream>>>(bsum, boff);
    scan3<<<NBLK, 256, 0, stream>>>(part, boff, deg, rowptr, cursor, inv);
    bucket_kernel<<<(N_EDGES + 255) / 256, 256, 0, stream>>>(src, dstn, cursor, eidx, N_EDGES);

    int mblocks = (N_NODES + 63) / 64;
    int ablocks = (N_NODES + 3) / 4;
    // Layer 0
    gemm_sage<<<mblocks, 256, 0, stream>>>(xb, Wp, Wp + 16384, b0l, mb, sbuf, N_NODES);
    agg_combine<1><<<ablocks, 256, 0, stream>>>(mb, rowptr, eidx, inv, sbuf, hb, nullptr);
    // Layer 1
    gemm_sage<<<mblocks, 256, 0, stream>>>(hb, Wp + 2 * 16384, Wp + 3 * 16384, b1l, mb, sbuf, N_NODES);
    agg_combine<0><<<ablocks, 256, 0, stream>>>(mb, rowptr, eidx, inv, sbuf, nullptr, out);
}

// Round 4
// 276.893 us; speedup vs baseline: 20.8751x; 1.0972x over previous
//
#include <hip/hip_runtime.h>

#define N_NODES 50000
#define N_EDGES 800000
#define D 128
#define NBLK ((N_NODES + 255) / 256)   // 196 coarse buckets / scan blocks
#define EPB 4096                        // edges per bucket_coarse block

typedef __bf16 bf16x8 __attribute__((ext_vector_type(8)));
typedef short s16x8 __attribute__((ext_vector_type(8)));
typedef float f32x4 __attribute__((ext_vector_type(4)));
typedef unsigned short u16;
typedef unsigned int u32;

__device__ inline u16 f32_to_bf16(float f) {
    u32 u = __builtin_bit_cast(u32, f);
    u += 0x7fffu + ((u >> 16) & 1u);   // round-to-nearest-even
    return (u16)(u >> 16);
}
__device__ inline float bf16_lo(u32 v) { return __builtin_bit_cast(float, v << 16); }
__device__ inline float bf16_hi(u32 v) { return __builtin_bit_cast(float, v & 0xffff0000u); }

__device__ inline f32x4 mfma16(s16x8 a, s16x8 b, f32x4 c) {
    return __builtin_amdgcn_mfma_f32_16x16x32_bf16(
        __builtin_bit_cast(bf16x8, a), __builtin_bit_cast(bf16x8, b), c, 0, 0, 0);
}

// Pack W (128x128 f32, row-major W[k][n]) into MFMA B-fragment order.
__global__ void prep_weights(const float* __restrict__ W0l, const float* __restrict__ W0r,
                             const float* __restrict__ W1l, const float* __restrict__ W1r,
                             u16* __restrict__ Wp) {
    int gid = blockIdx.x * blockDim.x + threadIdx.x;
    if (gid >= 4 * 2048) return;
    int wsel = gid >> 11;
    int rem  = gid & 2047;
    int ct   = rem >> 8;         // 0..7
    int ks   = (rem >> 6) & 3;   // 0..3
    int lane = rem & 63;
    const float* W = (wsel == 0) ? W0l : (wsel == 1) ? W0r : (wsel == 2) ? W1l : W1r;
    int n  = ct * 16 + (lane & 15);
    int k0 = ks * 32 + (lane >> 4) * 8;
    u16 o[8];
#pragma unroll
    for (int j = 0; j < 8; j++) o[j] = f32_to_bf16(W[(k0 + j) * D + n]);
    u16* dst = Wp + wsel * 16384 + (size_t)((ct * 4 + ks) * 64 + lane) * 8;
    *(s16x8*)dst = *(const s16x8*)o;
}

__global__ void cast_f32_bf16(const float* __restrict__ x, u16* __restrict__ xb, int n8) {
    int gid = blockIdx.x * blockDim.x + threadIdx.x;
    if (gid >= n8) return;
    const float* p = x + (size_t)gid * 8;
    f32x4 a = *(const f32x4*)p;
    f32x4 b = *(const f32x4*)(p + 4);
    u16 o[8];
#pragma unroll
    for (int j = 0; j < 4; j++) { o[j] = f32_to_bf16(a[j]); o[4 + j] = f32_to_bf16(b[j]); }
    *(s16x8*)(xb + (size_t)gid * 8) = *(const s16x8*)o;
}

__global__ void deg_kernel(const int* __restrict__ dst, int* __restrict__ deg, int n) {
    int gid = blockIdx.x * blockDim.x + threadIdx.x;
    if (gid < n) atomicAdd(&deg[dst[gid]], 1);
}

// Level 1: per-256-node block exclusive scan, emit block totals.
__global__ __launch_bounds__(256) void scan1(const int* __restrict__ deg,
                                             int* __restrict__ part,
                                             int* __restrict__ blocksum) {
    int t = threadIdx.x, b = blockIdx.x;
    int idx = b * 256 + t;
    int v = (idx < N_NODES) ? deg[idx] : 0;
    int lane = t & 63, wave = t >> 6;
    int s = v;
#pragma unroll
    for (int off = 1; off < 64; off <<= 1) {
        int u = __shfl_up(s, off, 64);
        if (lane >= off) s += u;
    }
    __shared__ int wsum[4];
    if (lane == 63) wsum[wave] = s;
    __syncthreads();
    int wadd = 0;
#pragma unroll
    for (int w = 0; w < 4; w++) if (w < wave) wadd += wsum[w];
    if (idx < N_NODES) part[idx] = s - v + wadd;   // exclusive within block
    if (t == 255) blocksum[b] = wadd + s;
}

// Level 2+3 merged: every block redundantly scans the 196 block sums, then applies
// its own offset; writes rowptr, coarse cursors, inv_deg.
__global__ __launch_bounds__(256) void scan23(const int* __restrict__ part,
                                              const int* __restrict__ bsum,
                                              const int* __restrict__ deg,
                                              int* __restrict__ rowptr,
                                              int* __restrict__ ccursor,
                                              float* __restrict__ inv) {
    __shared__ int sc[256];
    __shared__ int wsum[4];
    int t = threadIdx.x, b = blockIdx.x;
    int v = (t < NBLK) ? bsum[t] : 0;
    int lane = t & 63, wave = t >> 6;
    int s = v;
#pragma unroll
    for (int off = 1; off < 64; off <<= 1) {
        int u = __shfl_up(s, off, 64);
        if (lane >= off) s += u;
    }
    if (lane == 63) wsum[wave] = s;
    __syncthreads();
    int wadd = 0;
#pragma unroll
    for (int w = 0; w < 4; w++) if (w < wave) wadd += wsum[w];
    sc[t] = s - v + wadd;          // exclusive scan of block sums
    __syncthreads();
    int boff = sc[b];
    int idx = b * 256 + t;
    if (idx < N_NODES) {
        int r = part[idx] + boff;
        rowptr[idx] = r;
        int d = deg[idx];
        inv[idx] = d > 0 ? 1.0f / (float)d : 0.0f;
        if (t == 0) ccursor[b] = r;     // coarse region base = rowptr[b*256]
    }
    if (b == 0 && t == 0) rowptr[N_NODES] = N_EDGES;  // all dst in-range
}

// Bucket pass 1: coarse-bucket edges by dst>>8 with block-local chunk reservation
// (one global atomic per (block, coarse-bucket)) -> contiguous small writes.
__global__ __launch_bounds__(256) void bucket_coarse(const int* __restrict__ src,
                                                     const int* __restrict__ dst,
                                                     int* __restrict__ ccursor,
                                                     u32* __restrict__ staged) {
    __shared__ int hist[NBLK];
    __shared__ int base[NBLK];
    int t = threadIdx.x, b = blockIdx.x;
    int bb = b * EPB;
    if (t < NBLK) hist[t] = 0;
    __syncthreads();
    u32 pk[16]; int cb[16];
#pragma unroll
    for (int i = 0; i < 16; i++) {
        int e = bb + i * 256 + t;
        if (e < N_EDGES) {
            int sv = src[e], dv = dst[e];
            pk[i] = (u32)sv | ((u32)(dv & 255) << 16);
            cb[i] = dv >> 8;
            atomicAdd(&hist[cb[i]], 1);
        } else cb[i] = -1;
    }
    __syncthreads();
    if (t < NBLK) {
        int c = hist[t];
        base[t] = (c > 0) ? atomicAdd(&ccursor[t], c) : 0;
        hist[t] = 0;                 // reuse as intra-block offset counters
    }
    __syncthreads();
#pragma unroll
    for (int i = 0; i < 16; i++) {
        if (cb[i] >= 0) {
            int slot = atomicAdd(&hist[cb[i]], 1);
            staged[base[cb[i]] + slot] = pk[i];
        }
    }
}

// Bucket pass 2: one block per coarse bucket; scatter to final CSR slots via LDS
// cursors (writes stay inside an 8KB single-XCD window -> no HBM amplification).
__global__ __launch_bounds__(256) void bucket_fine(const int* __restrict__ rowptr,
                                                   const u32* __restrict__ staged,
                                                   u16* __restrict__ eidx) {
    __shared__ int fc[256];
    int t = threadIdx.x, cb = blockIdx.x;
    int n = cb * 256 + t;
    fc[t] = (n < N_NODES) ? rowptr[n] : 0;
    int s = rowptr[cb * 256];
    int endn = cb * 256 + 256;
    int e = rowptr[endn <= N_NODES ? endn : N_NODES];
    __syncthreads();
    for (int i = s + t; i < e; i += 256) {
        u32 v = staged[i];
        int pos = atomicAdd(&fc[(v >> 16) & 255], 1);
        eidx[pos] = (u16)(v & 0xffffu);
    }
}

// One wave per destination node: gather h[src] rows via CSR, mean in f32, write bf16.
__global__ __launch_bounds__(256) void agg_mean(const u16* __restrict__ h,
                                                const int* __restrict__ rowptr,
                                                const u16* __restrict__ eidx,
                                                const float* __restrict__ inv,
                                                u16* __restrict__ mean) {
    int wave = threadIdx.x >> 6, lane = threadIdx.x & 63;
    int node = blockIdx.x * 4 + wave;
    if (node >= N_NODES) return;
    int start = rowptr[node], end = rowptr[node + 1];

    float a0 = 0.f, a1 = 0.f;
    int e = start;
    for (; e + 3 < end; e += 4) {
        int s0 = eidx[e], s1 = eidx[e + 1], s2 = eidx[e + 2], s3 = eidx[e + 3];
        u32 v0 = *(const u32*)(h + (size_t)s0 * D + lane * 2);
        u32 v1 = *(const u32*)(h + (size_t)s1 * D + lane * 2);
        u32 v2 = *(const u32*)(h + (size_t)s2 * D + lane * 2);
        u32 v3 = *(const u32*)(h + (size_t)s3 * D + lane * 2);
        a0 += bf16_lo(v0) + bf16_lo(v1) + bf16_lo(v2) + bf16_lo(v3);
        a1 += bf16_hi(v0) + bf16_hi(v1) + bf16_hi(v2) + bf16_hi(v3);
    }
    for (; e < end; e++) {
        u32 v0 = *(const u32*)(h + (size_t)eidx[e] * D + lane * 2);
        a0 += bf16_lo(v0);
        a1 += bf16_hi(v0);
    }
    float iv = inv[node];
    u32 packed = (u32)f32_to_bf16(a0 * iv) | ((u32)f32_to_bf16(a1 * iv) << 16);
    *(u32*)(mean + (size_t)node * D + lane * 2) = packed;
}

// Fused SAGE layer GEMM: out = A1@Wr + A2@Wl + mask*b  (A2 = mean of neighbors).
// Block: 64 rows x 128 cols; wave w owns cols [w*32, w*32+32).
template <int RELU, int OUTF32>
__global__ __launch_bounds__(256) void gemm_fused(
    const u16* __restrict__ A1, const u16* __restrict__ A2,
    const u16* __restrict__ WpR, const u16* __restrict__ WpL,
    const float* __restrict__ bias, const float* __restrict__ inv,
    u16* __restrict__ outb, float* __restrict__ outf, int M) {
    int wave = threadIdx.x >> 6, lane = threadIdx.x & 63;
    int rowbase = blockIdx.x * 64;
    int lrow = lane & 15, quad = lane >> 4;

    s16x8 bR[2][4], bL[2][4];
#pragma unroll
    for (int ct = 0; ct < 2; ct++) {
        int ctg = wave * 2 + ct;
#pragma unroll
        for (int ks = 0; ks < 4; ks++) {
            size_t off = (size_t)((ctg * 4 + ks) * 64 + lane) * 8;
            bR[ct][ks] = *(const s16x8*)(WpR + off);
            bL[ct][ks] = *(const s16x8*)(WpL + off);
        }
    }

    f32x4 acc[4][2];
#pragma unroll
    for (int rt = 0; rt < 4; rt++)
#pragma unroll
        for (int ct = 0; ct < 2; ct++) acc[rt][ct] = (f32x4){0.f, 0.f, 0.f, 0.f};

#pragma unroll
    for (int ks = 0; ks < 4; ks++) {
        s16x8 a1[4], a2[4];
#pragma unroll
        for (int rt = 0; rt < 4; rt++) {
            int row = rowbase + rt * 16 + lrow;
            row = row < M ? row : M - 1;
            a1[rt] = *(const s16x8*)(A1 + (size_t)row * D + ks * 32 + quad * 8);
            a2[rt] = *(const s16x8*)(A2 + (size_t)row * D + ks * 32 + quad * 8);
        }
#pragma unroll
        for (int rt = 0; rt < 4; rt++)
#pragma unroll
            for (int ct = 0; ct < 2; ct++) {
                acc[rt][ct] = mfma16(a1[rt], bR[ct][ks], acc[rt][ct]);
                acc[rt][ct] = mfma16(a2[rt], bL[ct][ks], acc[rt][ct]);
            }
    }

    float bv[2];
#pragma unroll
    for (int ct = 0; ct < 2; ct++) bv[ct] = bias[wave * 32 + ct * 16 + lrow];

#pragma unroll
    for (int rt = 0; rt < 4; rt++) {
#pragma unroll
        for (int i = 0; i < 4; i++) {
            int row = rowbase + rt * 16 + quad * 4 + i;
            if (row >= M) continue;
            float mask = inv[row] > 0.f ? 1.f : 0.f;
#pragma unroll
            for (int ct = 0; ct < 2; ct++) {
                int col = wave * 32 + ct * 16 + lrow;
                float v = acc[rt][ct][i] + mask * bv[ct];
                if (RELU) v = v > 0.f ? v : 0.f;
                if (OUTF32) outf[(size_t)row * D + col] = v;
                else        outb[(size_t)row * D + col] = f32_to_bf16(v);
            }
        }
    }
}

extern "C" void kernel_launch(void* const* d_in, const int* in_sizes, int n_in,
                              void* d_out, int out_size, void* d_ws, size_t ws_size,
                              hipStream_t stream) {
    const float* x    = (const float*)d_in[0];
    const int*   edge = (const int*)d_in[1];
    const int*   src  = edge;
    const int*   dstn = edge + N_EDGES;
    const float* W0l  = (const float*)d_in[2];
    const float* b0l  = (const float*)d_in[3];
    const float* W0r  = (const float*)d_in[4];
    const float* W1l  = (const float*)d_in[5];
    const float* b1l  = (const float*)d_in[6];
    const float* W1r  = (const float*)d_in[7];
    float* out = (float*)d_out;

    char* p = (char*)d_ws;
    auto alloc = [&](size_t nb) { char* r = p; p += (nb + 255) & ~(size_t)255; return r; };
    int*   deg     = (int*)alloc((size_t)N_NODES * 4);
    int*   part    = (int*)alloc((size_t)N_NODES * 4);
    int*   bsum    = (int*)alloc((size_t)NBLK * 4);
    int*   rowptr  = (int*)alloc((size_t)(N_NODES + 1) * 4);
    int*   ccursor = (int*)alloc((size_t)NBLK * 4);
    u32*   staged  = (u32*)alloc((size_t)N_EDGES * 4);
    u16*   eidx    = (u16*)alloc((size_t)N_EDGES * 2);
    float* inv     = (float*)alloc((size_t)N_NODES * 4);
    u16*   xb      = (u16*)alloc((size_t)N_NODES * D * 2);
    u16*   hb      = (u16*)alloc((size_t)N_NODES * D * 2);
    u16*   meanb   = (u16*)alloc((size_t)N_NODES * D * 2);
    u16*   Wp      = (u16*)alloc((size_t)4 * 16384 * 2);

    hipMemsetAsync(deg, 0, (size_t)N_NODES * 4, stream);

    prep_weights<<<(8192 + 255) / 256, 256, 0, stream>>>(W0l, W0r, W1l, W1r, Wp);
    cast_f32_bf16<<<(N_NODES * 16 + 255) / 256, 256, 0, stream>>>(x, xb, N_NODES * 16);
    deg_kernel<<<(N_EDGES + 255) / 256, 256, 0, stream>>>(dstn, deg, N_EDGES);
    scan1<<<NBLK, 256, 0, stream>>>(deg, part, bsum);
    scan23<<<NBLK, 256, 0, stream>>>(part, bsum, deg, rowptr, ccursor, inv);
    bucket_coarse<<<(N_EDGES + EPB - 1) / EPB, 256, 0, stream>>>(src, dstn, ccursor, staged);
    bucket_fine<<<NBLK, 256, 0, stream>>>(rowptr, staged, eidx);

    int mblocks = (N_NODES + 63) / 64;
    int ablocks = (N_NODES + 3) / 4;
    const u16* WpL0 = Wp;                 // W0l
    const u16* WpR0 = Wp + 16384;         // W0r
    const u16* WpL1 = Wp + 2 * 16384;     // W1l
    const u16* WpR1 = Wp + 3 * 16384;     // W1r
    // Layer 0: h = relu( x@W0r + mean_x@W0l + mask*b0l )
    agg_mean<<<ablocks, 256, 0, stream>>>(xb, rowptr, eidx, inv, meanb);
    gemm_fused<1, 0><<<mblocks, 256, 0, stream>>>(xb, meanb, WpR0, WpL0, b0l, inv, hb, nullptr, N_NODES);
    // Layer 1: out = h@W1r + mean_h@W1l + mask*b1l
    agg_mean<<<ablocks, 256, 0, stream>>>(hb, rowptr, eidx, inv, meanb);
    gemm_fused<0, 1><<<mblocks, 256, 0, stream>>>(hb, meanb, WpR1, WpL1, b1l, inv, nullptr, out, N_NODES);
}